// Round 1
// baseline (2954.754 us; speedup 1.0000x reference)
//
#include <hip/hip_runtime.h>
#include <hip/hip_bf16.h>
#include <cstdint>

#define BATCH 4096
#define DIM   512
#define HID   1024
#define TSTEPS 20

typedef unsigned short u16;
typedef short s16x8 __attribute__((ext_vector_type(8)));
typedef float f32x4 __attribute__((ext_vector_type(4)));

__device__ __forceinline__ u16 f2bf(float f) {
    unsigned int u = __float_as_uint(f);
    u = (u + 0x7FFFu + ((u >> 16) & 1u)) >> 16;   // RNE
    return (u16)u;
}

// out[0] = x0 ; ybf = bf16(x0)
__global__ void init_state(const float* __restrict__ x0, float* __restrict__ out0,
                           u16* __restrict__ ybf, int n) {
    int i = blockIdx.x * blockDim.x + threadIdx.x;
    if (i < n) { float v = x0[i]; out0[i] = v; ybf[i] = f2bf(v); }
}

// Wt[n*K + k] = bf16(W[k*N + n])   (W is [K][N] row-major)
__global__ void transpose_convert(const float* __restrict__ W, u16* __restrict__ Wt,
                                  int K, int N) {
    int n = blockIdx.x * 32 + threadIdx.x;
    int k = blockIdx.y * 8  + threadIdx.y;
    if (n < N && k < K) Wt[(size_t)n * K + k] = f2bf(W[(size_t)k * N + n]);
}

// C = A[M,K] * Bt[N,K]^T  with fused epilogue.
// EPI==0 : act = bf16(tanh(C + bias))           (GEMM1)
// EPI==1..4 : RK4 stage epilogues               (GEMM2, N == DIM)
template<int BM, int BN, int EPI>
__global__ __launch_bounds__(256) void gemm_bt(
    const u16* __restrict__ A,
    const u16* __restrict__ Bt,
    const float* __restrict__ bias,
    int M, int N, int K,
    u16* __restrict__ actOut,
    const float* __restrict__ ybase,
    float* __restrict__ ynext,
    float* __restrict__ accum,
    u16* __restrict__ ybf,
    const float* __restrict__ tgrid, int step)
{
    constexpr int AC = BM / 8;          // A chunks (1 KiB each) per K-tile
    constexpr int BC = BN / 8;
    constexpr int CPW = (AC + BC) / 4;  // chunks per wave
    constexpr int WM = BM / 32;         // 16x16 frags per wave (rows)
    constexpr int WN = BN / 32;         // 16x16 frags per wave (cols)

    __shared__ u16 lds[(BM + BN) * 64];

    const int tid  = threadIdx.x;
    const int lane = tid & 63;
    const int wid  = tid >> 6;
    const int wy   = wid >> 1;          // 2x2 wave grid
    const int wx   = wid & 1;
    const int brow = blockIdx.x * BM;
    const int bcol = blockIdx.y * BN;

    // staging: lane l fetches global 16B chunk at swizzled k-slot
    const int srow = lane >> 3;                    // row within 8-row group
    const int scol = ((lane & 7) ^ srow) * 8;      // pre-swizzled k offset (elems)

    f32x4 acc[WM][WN];
#pragma unroll
    for (int m = 0; m < WM; ++m)
#pragma unroll
        for (int n = 0; n < WN; ++n)
            acc[m][n] = (f32x4){0.f, 0.f, 0.f, 0.f};

    const char* ldsc = (const char*)lds;

    for (int kt = 0; kt < K / 64; ++kt) {
        __syncthreads();
        const int k0 = kt * 64;
#pragma unroll
        for (int c0 = 0; c0 < CPW; ++c0) {
            int c = wid * CPW + c0;
            if (c < AC) {
                int row = c * 8 + srow;
                const u16* g = A + (size_t)(brow + row) * K + k0 + scol;
                __builtin_amdgcn_global_load_lds(
                    (const __attribute__((address_space(1))) unsigned int*)g,
                    (__attribute__((address_space(3))) unsigned int*)&lds[c * 512],
                    16, 0, 0);
            } else {
                int cb = c - AC;
                int row = cb * 8 + srow;
                const u16* g = Bt + (size_t)(bcol + row) * K + k0 + scol;
                __builtin_amdgcn_global_load_lds(
                    (const __attribute__((address_space(1))) unsigned int*)g,
                    (__attribute__((address_space(3))) unsigned int*)&lds[BM * 64 + cb * 512],
                    16, 0, 0);
            }
        }
        __syncthreads();

#pragma unroll
        for (int ks = 0; ks < 2; ++ks) {
            s16x8 af[WM], bfr[WN];
#pragma unroll
            for (int m = 0; m < WM; ++m) {
                int row = wy * (BM / 2) + m * 16 + (lane & 15);
                unsigned byte = (unsigned)(row * 128 + (ks * 32 + (lane >> 4) * 8) * 2);
                byte ^= (unsigned)((row & 7) << 4);
                af[m] = *(const s16x8*)(ldsc + byte);
            }
#pragma unroll
            for (int n = 0; n < WN; ++n) {
                int row = wx * (BN / 2) + n * 16 + (lane & 15);
                unsigned byte = (unsigned)(BM * 128 + row * 128 + (ks * 32 + (lane >> 4) * 8) * 2);
                byte ^= (unsigned)((row & 7) << 4);
                bfr[n] = *(const s16x8*)(ldsc + byte);
            }
#pragma unroll
            for (int m = 0; m < WM; ++m)
#pragma unroll
                for (int n = 0; n < WN; ++n)
                    acc[m][n] = __builtin_amdgcn_mfma_f32_16x16x32_bf16(
                        af[m], bfr[n], acc[m][n], 0, 0, 0);
        }
    }

    // ---- epilogue ----
    float dtv = 0.f;
    if constexpr (EPI >= 1) dtv = tgrid[step + 1] - tgrid[step];

#pragma unroll
    for (int m = 0; m < WM; ++m) {
        int row0 = brow + wy * (BM / 2) + m * 16 + (lane >> 4) * 4;
#pragma unroll
        for (int n = 0; n < WN; ++n) {
            int col = bcol + wx * (BN / 2) + n * 16 + (lane & 15);
            float bv = bias[col];
#pragma unroll
            for (int j = 0; j < 4; ++j) {
                int row = row0 + j;
                float v = acc[m][n][j] + bv;
                if constexpr (EPI == 0) {
                    actOut[(size_t)row * HID + col] = f2bf(tanhf(v));
                } else {
                    size_t idx = (size_t)row * DIM + col;
                    float yb = ybase[idx];
                    if constexpr (EPI == 1) {
                        accum[idx] = v;
                        ybf[idx] = f2bf(yb + 0.5f * dtv * v);
                    } else if constexpr (EPI == 2) {
                        accum[idx] += 2.0f * v;
                        ybf[idx] = f2bf(yb + 0.5f * dtv * v);
                    } else if constexpr (EPI == 3) {
                        accum[idx] += 2.0f * v;
                        ybf[idx] = f2bf(yb + dtv * v);
                    } else {  // EPI == 4
                        float yn = yb + (dtv * (1.0f / 6.0f)) * (accum[idx] + v);
                        ynext[idx] = yn;
                        ybf[idx] = f2bf(yn);
                    }
                }
            }
        }
    }
}

extern "C" void kernel_launch(void* const* d_in, const int* in_sizes, int n_in,
                              void* d_out, int out_size, void* d_ws, size_t ws_size,
                              hipStream_t stream) {
    (void)in_sizes; (void)n_in; (void)out_size; (void)ws_size;
    const float* x0 = (const float*)d_in[0];
    const float* t  = (const float*)d_in[1];
    const float* W1 = (const float*)d_in[2];
    const float* b1 = (const float*)d_in[3];
    const float* W2 = (const float*)d_in[4];
    const float* b2 = (const float*)d_in[5];
    float* out = (float*)d_out;

    char* ws = (char*)d_ws;
    u16*   ybf   = (u16*)  (ws);               //  4 MB  [4096,512]  bf16
    u16*   act   = (u16*)  (ws + (4u  << 20)); //  8 MB  [4096,1024] bf16
    float* accum = (float*)(ws + (12u << 20)); //  8 MB  [4096,512]  f32
    u16*   W1T   = (u16*)  (ws + (20u << 20)); //  1 MB  [1024,512]  bf16
    u16*   W2T   = (u16*)  (ws + (21u << 20)); //  1 MB  [512,1024]  bf16

    init_state<<<(BATCH * DIM + 255) / 256, 256, 0, stream>>>(x0, out, ybf, BATCH * DIM);
    transpose_convert<<<dim3(HID / 32, DIM / 8), dim3(32, 8), 0, stream>>>(W1, W1T, DIM, HID);
    transpose_convert<<<dim3(DIM / 32, HID / 8), dim3(32, 8), 0, stream>>>(W2, W2T, HID, DIM);

    dim3 blk(256);
    dim3 g1(BATCH / 128, HID / 128);   // 32 x 8
    dim3 g2(BATCH / 128, DIM / 64);    // 32 x 8

    for (int s = 0; s < TSTEPS - 1; ++s) {
        const float* yb_s = out + (size_t)s * BATCH * DIM;
        float*       yn_s = out + (size_t)(s + 1) * BATCH * DIM;

        // stage 1: k1 = f(y)
        gemm_bt<128,128,0><<<g1, blk, 0, stream>>>(ybf, W1T, b1, BATCH, HID, DIM,
                                                   act, nullptr, nullptr, nullptr, nullptr, nullptr, 0);
        gemm_bt<128,64,1><<<g2, blk, 0, stream>>>(act, W2T, b2, BATCH, DIM, HID,
                                                  nullptr, yb_s, yn_s, accum, ybf, t, s);
        // stage 2: k2 = f(y + dt/2 * k1)
        gemm_bt<128,128,0><<<g1, blk, 0, stream>>>(ybf, W1T, b1, BATCH, HID, DIM,
                                                   act, nullptr, nullptr, nullptr, nullptr, nullptr, 0);
        gemm_bt<128,64,2><<<g2, blk, 0, stream>>>(act, W2T, b2, BATCH, DIM, HID,
                                                  nullptr, yb_s, yn_s, accum, ybf, t, s);
        // stage 3: k3 = f(y + dt/2 * k2)
        gemm_bt<128,128,0><<<g1, blk, 0, stream>>>(ybf, W1T, b1, BATCH, HID, DIM,
                                                   act, nullptr, nullptr, nullptr, nullptr, nullptr, 0);
        gemm_bt<128,64,3><<<g2, blk, 0, stream>>>(act, W2T, b2, BATCH, DIM, HID,
                                                  nullptr, yb_s, yn_s, accum, ybf, t, s);
        // stage 4: y' = y + dt/6 * (k1 + 2k2 + 2k3 + k4)
        gemm_bt<128,128,0><<<g1, blk, 0, stream>>>(ybf, W1T, b1, BATCH, HID, DIM,
                                                   act, nullptr, nullptr, nullptr, nullptr, nullptr, 0);
        gemm_bt<128,64,4><<<g2, blk, 0, stream>>>(act, W2T, b2, BATCH, DIM, HID,
                                                  nullptr, yb_s, yn_s, accum, ybf, t, s);
    }
}

// Round 2
// 2392.349 us; speedup vs baseline: 1.2351x; 1.2351x over previous
//
#include <hip/hip_runtime.h>
#include <hip/hip_bf16.h>
#include <cstdint>

#define BATCH 4096
#define DIM   512
#define HID   1024
#define TSTEPS 20

typedef unsigned short u16;
typedef short s16x8 __attribute__((ext_vector_type(8)));
typedef float f32x4 __attribute__((ext_vector_type(4)));

__device__ __forceinline__ u16 f2bf(float f) {
    unsigned int u = __float_as_uint(f);
    u = (u + 0x7FFFu + ((u >> 16) & 1u)) >> 16;   // RNE
    return (u16)u;
}

// out[0] = x0 ; ybf = bf16(x0)
__global__ void init_state(const float* __restrict__ x0, float* __restrict__ out0,
                           u16* __restrict__ ybf, int n) {
    int i = blockIdx.x * blockDim.x + threadIdx.x;
    if (i < n) { float v = x0[i]; out0[i] = v; ybf[i] = f2bf(v); }
}

// Wt[n*K + k] = bf16(W[k*N + n])   (W is [K][N] row-major)
__global__ void transpose_convert(const float* __restrict__ W, u16* __restrict__ Wt,
                                  int K, int N) {
    int n = blockIdx.x * 32 + threadIdx.x;
    int k = blockIdx.y * 8  + threadIdx.y;
    if (n < N && k < K) Wt[(size_t)n * K + k] = f2bf(W[(size_t)k * N + n]);
}

// C = A[M,K] * Bt[N,K]^T  with fused epilogue, 2-phase double-buffered K-loop.
// EPI==0 : act = bf16(tanh(C + bias))           (GEMM1)
// EPI==1..4 : RK4 stage epilogues               (GEMM2, N == DIM)
template<int BM, int BN, int EPI>
__global__ __launch_bounds__(256, 2) void gemm_bt(
    const u16* __restrict__ A,
    const u16* __restrict__ Bt,
    const float* __restrict__ bias,
    int M, int N, int K,
    u16* __restrict__ actOut,
    const float* __restrict__ ybase,
    float* __restrict__ ynext,
    float* __restrict__ accum,
    u16* __restrict__ ybf,
    const float* __restrict__ tgrid, int step)
{
    constexpr int AC = BM / 8;          // A chunks (1 KiB each) per K-tile
    constexpr int BC = BN / 8;
    constexpr int CPW = (AC + BC) / 4;  // chunks per wave
    constexpr int WM = BM / 32;         // 16x16 frags per wave (rows)
    constexpr int WN = BN / 32;         // 16x16 frags per wave (cols)
    constexpr int BUFE = (BM + BN) * 64;   // u16 elems per LDS buffer

    __shared__ u16 lds[2 * BUFE];

    const int tid  = threadIdx.x;
    const int lane = tid & 63;
    const int wid  = tid >> 6;
    const int wy   = wid >> 1;          // 2x2 wave grid
    const int wx   = wid & 1;
    const int brow = blockIdx.x * BM;
    const int bcol = blockIdx.y * BN;

    // staging: lane l fetches global 16B chunk at swizzled k-slot
    const int srow = lane >> 3;                    // row within 8-row group
    const int scol = ((lane & 7) ^ srow) * 8;      // pre-swizzled k offset (elems)

    f32x4 acc[WM][WN];
#pragma unroll
    for (int m = 0; m < WM; ++m)
#pragma unroll
        for (int n = 0; n < WN; ++n)
            acc[m][n] = (f32x4){0.f, 0.f, 0.f, 0.f};

    auto stage = [&](int buf, int kt) {
        const int k0 = kt * 64;
        u16* base = &lds[buf * BUFE];
#pragma unroll
        for (int c0 = 0; c0 < CPW; ++c0) {
            int c = wid * CPW + c0;            // wave-uniform
            if (c < AC) {
                int row = c * 8 + srow;
                const u16* g = A + (size_t)(brow + row) * K + k0 + scol;
                __builtin_amdgcn_global_load_lds(
                    (const __attribute__((address_space(1))) unsigned int*)g,
                    (__attribute__((address_space(3))) unsigned int*)&base[c * 512],
                    16, 0, 0);
            } else {
                int cb = c - AC;
                int row = cb * 8 + srow;
                const u16* g = Bt + (size_t)(bcol + row) * K + k0 + scol;
                __builtin_amdgcn_global_load_lds(
                    (const __attribute__((address_space(1))) unsigned int*)g,
                    (__attribute__((address_space(3))) unsigned int*)&base[BM * 64 + cb * 512],
                    16, 0, 0);
            }
        }
    };

    const int NT = K / 64;

    // prologue: stage K-tile 0 into buffer 0
    stage(0, 0);
    asm volatile("s_waitcnt vmcnt(0)" ::: "memory");
    __builtin_amdgcn_s_barrier();

    int cur = 0;
    for (int kt = 0; kt < NT; ++kt) {
        const char* lb = (const char*)&lds[cur * BUFE];

        // ds_read current tile's fragments (both K-slices)
        s16x8 af[2][WM], bfr[2][WN];
#pragma unroll
        for (int ks = 0; ks < 2; ++ks) {
#pragma unroll
            for (int m = 0; m < WM; ++m) {
                int row = wy * (BM / 2) + m * 16 + (lane & 15);
                unsigned byte = (unsigned)(row * 128 + (ks * 32 + (lane >> 4) * 8) * 2);
                byte ^= (unsigned)((row & 7) << 4);
                af[ks][m] = *(const s16x8*)(lb + byte);
            }
#pragma unroll
            for (int n = 0; n < WN; ++n) {
                int row = wx * (BN / 2) + n * 16 + (lane & 15);
                unsigned byte = (unsigned)(BM * 128 + row * 128 + (ks * 32 + (lane >> 4) * 8) * 2);
                byte ^= (unsigned)((row & 7) << 4);
                bfr[ks][n] = *(const s16x8*)(lb + byte);
            }
        }

        // issue next K-tile's staging while ds_reads/MFMA proceed
        if (kt + 1 < NT) stage(cur ^ 1, kt + 1);

#pragma unroll
        for (int ks = 0; ks < 2; ++ks)
#pragma unroll
            for (int m = 0; m < WM; ++m)
#pragma unroll
                for (int n = 0; n < WN; ++n)
                    acc[m][n] = __builtin_amdgcn_mfma_f32_16x16x32_bf16(
                        af[ks][m], bfr[ks][n], acc[m][n], 0, 0, 0);

        asm volatile("s_waitcnt vmcnt(0)" ::: "memory");
        __builtin_amdgcn_s_barrier();
        cur ^= 1;
    }

    // ---- epilogue ----
    float dtv = 0.f;
    if constexpr (EPI >= 1) dtv = tgrid[step + 1] - tgrid[step];

#pragma unroll
    for (int m = 0; m < WM; ++m) {
        int row0 = brow + wy * (BM / 2) + m * 16 + (lane >> 4) * 4;
#pragma unroll
        for (int n = 0; n < WN; ++n) {
            int col = bcol + wx * (BN / 2) + n * 16 + (lane & 15);
            float bv = bias[col];
#pragma unroll
            for (int j = 0; j < 4; ++j) {
                int row = row0 + j;
                float v = acc[m][n][j] + bv;
                if constexpr (EPI == 0) {
                    actOut[(size_t)row * HID + col] = f2bf(tanhf(v));
                } else {
                    size_t idx = (size_t)row * DIM + col;
                    float yb = ybase[idx];
                    if constexpr (EPI == 1) {
                        accum[idx] = v;
                        ybf[idx] = f2bf(yb + 0.5f * dtv * v);
                    } else if constexpr (EPI == 2) {
                        accum[idx] += 2.0f * v;
                        ybf[idx] = f2bf(yb + 0.5f * dtv * v);
                    } else if constexpr (EPI == 3) {
                        accum[idx] += 2.0f * v;
                        ybf[idx] = f2bf(yb + dtv * v);
                    } else {  // EPI == 4
                        float yn = yb + (dtv * (1.0f / 6.0f)) * (accum[idx] + v);
                        ynext[idx] = yn;
                        ybf[idx] = f2bf(yn);
                    }
                }
            }
        }
    }
}

extern "C" void kernel_launch(void* const* d_in, const int* in_sizes, int n_in,
                              void* d_out, int out_size, void* d_ws, size_t ws_size,
                              hipStream_t stream) {
    (void)in_sizes; (void)n_in; (void)out_size; (void)ws_size;
    const float* x0 = (const float*)d_in[0];
    const float* t  = (const float*)d_in[1];
    const float* W1 = (const float*)d_in[2];
    const float* b1 = (const float*)d_in[3];
    const float* W2 = (const float*)d_in[4];
    const float* b2 = (const float*)d_in[5];
    float* out = (float*)d_out;

    char* ws = (char*)d_ws;
    u16*   ybf   = (u16*)  (ws);               //  4 MB  [4096,512]  bf16
    u16*   act   = (u16*)  (ws + (4u  << 20)); //  8 MB  [4096,1024] bf16
    float* accum = (float*)(ws + (12u << 20)); //  8 MB  [4096,512]  f32
    u16*   W1T   = (u16*)  (ws + (20u << 20)); //  1 MB  [1024,512]  bf16
    u16*   W2T   = (u16*)  (ws + (21u << 20)); //  1 MB  [512,1024]  bf16

    init_state<<<(BATCH * DIM + 255) / 256, 256, 0, stream>>>(x0, out, ybf, BATCH * DIM);
    transpose_convert<<<dim3(HID / 32, DIM / 8), dim3(32, 8), 0, stream>>>(W1, W1T, DIM, HID);
    transpose_convert<<<dim3(DIM / 32, HID / 8), dim3(32, 8), 0, stream>>>(W2, W2T, HID, DIM);

    dim3 blk(256);
    dim3 g1(BATCH / 128, HID / 64);    // 32 x 16 = 512 blocks (2 per CU)
    dim3 g2(BATCH / 64,  DIM / 64);    // 64 x 8  = 512 blocks (2 per CU)

    for (int s = 0; s < TSTEPS - 1; ++s) {
        const float* yb_s = out + (size_t)s * BATCH * DIM;
        float*       yn_s = out + (size_t)(s + 1) * BATCH * DIM;

        // stage 1: k1 = f(y)
        gemm_bt<128,64,0><<<g1, blk, 0, stream>>>(ybf, W1T, b1, BATCH, HID, DIM,
                                                  act, nullptr, nullptr, nullptr, nullptr, nullptr, 0);
        gemm_bt<64,64,1><<<g2, blk, 0, stream>>>(act, W2T, b2, BATCH, DIM, HID,
                                                 nullptr, yb_s, yn_s, accum, ybf, t, s);
        // stage 2: k2 = f(y + dt/2 * k1)
        gemm_bt<128,64,0><<<g1, blk, 0, stream>>>(ybf, W1T, b1, BATCH, HID, DIM,
                                                  act, nullptr, nullptr, nullptr, nullptr, nullptr, 0);
        gemm_bt<64,64,2><<<g2, blk, 0, stream>>>(act, W2T, b2, BATCH, DIM, HID,
                                                 nullptr, yb_s, yn_s, accum, ybf, t, s);
        // stage 3: k3 = f(y + dt/2 * k2)
        gemm_bt<128,64,0><<<g1, blk, 0, stream>>>(ybf, W1T, b1, BATCH, HID, DIM,
                                                  act, nullptr, nullptr, nullptr, nullptr, nullptr, 0);
        gemm_bt<64,64,3><<<g2, blk, 0, stream>>>(act, W2T, b2, BATCH, DIM, HID,
                                                 nullptr, yb_s, yn_s, accum, ybf, t, s);
        // stage 4: y' = y + dt/6 * (k1 + 2k2 + 2k3 + k4)
        gemm_bt<128,64,0><<<g1, blk, 0, stream>>>(ybf, W1T, b1, BATCH, HID, DIM,
                                                  act, nullptr, nullptr, nullptr, nullptr, nullptr, 0);
        gemm_bt<64,64,4><<<g2, blk, 0, stream>>>(act, W2T, b2, BATCH, DIM, HID,
                                                 nullptr, yb_s, yn_s, accum, ybf, t, s);
    }
}